// Round 5
// baseline (257.207 us; speedup 1.0000x reference)
//
#include <hip/hip_runtime.h>
#include <hip/hip_bf16.h>

#define N_Z 16384
#define M_E 4096
#define DIM 256
#define NB 2048                      // value buckets for wise kernel
#define NZH 8192                     // half column
#define BMIN (-6.0f)
#define BSCALE ((float)NB / 12.0f)   // buckets per unit (inexact; fixed up)
#define BW (12.0f / (float)NB)       // bucket width (exact: 3*2^-9)

typedef __bf16 bf16x8 __attribute__((ext_vector_type(8)));
typedef float f32x4 __attribute__((ext_vector_type(4)));

__device__ __forceinline__ unsigned short f2bf(float f) {
  unsigned u = __float_as_uint(f);
  u = (u + 0x7FFFu + ((u >> 16) & 1u)) >> 16;
  return (unsigned short)u;
}

__device__ __forceinline__ void gl2lds16(const void* g, void* s) {
  __builtin_amdgcn_global_load_lds(
      (const __attribute__((address_space(1))) unsigned*)g,
      (__attribute__((address_space(3))) unsigned*)s, 16, 0, 0);
}

// bucket edges edge(k) = BMIN + k*BW are EXACT in f32 ((3k-3072)*2^-9),
// so fix up the inexact *BSCALE rounding to make slice bounds sound.
__device__ __forceinline__ int bucketFix(float v) {
  int b = (int)((v - BMIN) * BSCALE);
  b = min(max(b, 0), NB - 1);
  while (b > 0 && v < BMIN + (float)b * BW) --b;
  while (b < NB - 1 && v >= BMIN + (float)(b + 1) * BW) ++b;
  return b;
}

// ---------------- init ----------------
__global__ void init_kernel(unsigned* __restrict__ d2min, float* __restrict__ wise_part,
                            float* __restrict__ z2, float* __restrict__ e2) {
  int i = blockIdx.x * blockDim.x + threadIdx.x;
  if (i < M_E) d2min[i] = 0x7F800000u;
  if (i < 64) wise_part[i] = 0.0f;
  if (i < N_Z) z2[i] = 0.0f;
  if (i < M_E) e2[i] = 0.0f;
}

// ---------------- fused prep: read once -> bf16 copy + transpose + row sq-norm ----------------
__global__ void prep_kernel(const float* __restrict__ in, float* __restrict__ outT,
                            unsigned short* __restrict__ outB, float* __restrict__ rsum, int R) {
  __shared__ float tile[32][33];
  __shared__ float rp[32];
  int r0 = blockIdx.x * 32, c0 = blockIdx.y * 32;
  int tx = threadIdx.x, ty = threadIdx.y;
  int lt = ty * 32 + tx;
  if (lt < 32) rp[lt] = 0.0f;
  __syncthreads();
#pragma unroll
  for (int i = 0; i < 4; ++i) {
    int rr = ty + 8 * i;
    float v = in[(size_t)(r0 + rr) * DIM + c0 + tx];
    tile[rr][tx] = v;
    outB[(size_t)(r0 + rr) * DIM + c0 + tx] = f2bf(v);
    atomicAdd(&rp[rr], v * v);
  }
  __syncthreads();
#pragma unroll
  for (int i = 0; i < 4; ++i)
    outT[(size_t)(c0 + ty + 8 * i) * R + r0 + tx] = tile[tx][ty + 8 * i];
  if (lt < 32) atomicAdd(&rsum[r0 + lt], rp[lt]);
}

// ---------------- fused bf16 GEMM (z . e^T) + min over n, per m ----------------
__global__ __launch_bounds__(256, 2) void gemm_min_kernel(
    const unsigned short* __restrict__ zb, const unsigned short* __restrict__ eb,
    const float* __restrict__ z2, const float* __restrict__ e2,
    unsigned* __restrict__ d2min) {
  __shared__ __align__(16) unsigned short lA[128 * 32];
  __shared__ __align__(16) unsigned short lB[128 * 32];

  const int t = threadIdx.x;
  const int w = t >> 6;
  const int l = t & 63;
  const int wr = w >> 1, wc = w & 1;
  int flat = blockIdx.y * 32 + blockIdx.x;
  int nf = (flat >> 3) + (flat & 7) * 512;
  const int tileM = (nf & 31) * 128;
  const int tileN = (nf >> 5) * 128;
  const int l15 = l & 15;
  const int kgr = l >> 4;

  f32x4 acc[4][4];
#pragma unroll
  for (int i = 0; i < 4; ++i)
#pragma unroll
    for (int j = 0; j < 4; ++j) acc[i][j] = (f32x4){0.f, 0.f, 0.f, 0.f};

#pragma unroll 1
  for (int k0 = 0; k0 < DIM; k0 += 32) {
#pragma unroll
    for (int i = 0; i < 2; ++i) {
      int c = i * 256 + t;
      int row = c >> 2;
      int kc = c & 3;
      int ldsbase = (i * 256 + (t & ~63)) * 8;
      gl2lds16(zb + (size_t)(tileN + row) * DIM + (k0 + kc * 8), &lA[ldsbase]);
      gl2lds16(eb + (size_t)(tileM + row) * DIM + (k0 + kc * 8), &lB[ldsbase]);
    }
    __syncthreads();

    bf16x8 a[4], b[4];
#pragma unroll
    for (int mi = 0; mi < 4; ++mi)
      a[mi] = *(const bf16x8*)&lA[(wr * 64 + mi * 16 + l15) * 32 + kgr * 8];
#pragma unroll
    for (int ni = 0; ni < 4; ++ni)
      b[ni] = *(const bf16x8*)&lB[(wc * 64 + ni * 16 + l15) * 32 + kgr * 8];
#pragma unroll
    for (int mi = 0; mi < 4; ++mi)
#pragma unroll
      for (int ni = 0; ni < 4; ++ni)
        acc[mi][ni] = __builtin_amdgcn_mfma_f32_16x16x32_bf16(a[mi], b[ni], acc[mi][ni], 0, 0, 0);
    __syncthreads();
  }

  float* z2s = (float*)lA;
  if (t < 128) z2s[t] = z2[tileN + t];
  __syncthreads();

#pragma unroll
  for (int ni = 0; ni < 4; ++ni) {
    float v = 3.4e38f;
#pragma unroll
    for (int mi = 0; mi < 4; ++mi)
#pragma unroll
      for (int r = 0; r < 4; ++r) {
        int rloc = wr * 64 + mi * 16 + kgr * 4 + r;
        v = fminf(v, z2s[rloc] - 2.0f * acc[mi][ni][r]);
      }
    v = fminf(v, __shfl_xor(v, 16));
    v = fminf(v, __shfl_xor(v, 32));
    if (l < 16) {
      int m = tileM + wc * 64 + ni * 16 + l;
      float d2 = v + e2[m];
      atomicMin(&d2min[m], __float_as_uint(d2));
    }
  }
}

// exclusive scan over arr[NB] (2 buckets/thread, 1024 threads); wsum = 16 scratch words
__device__ __forceinline__ void excl_scan_nb(unsigned* arr, unsigned* wsum, int t) {
  unsigned c0 = arr[2 * t], c1 = arr[2 * t + 1];
  unsigned ts2 = c0 + c1, s = ts2;
#pragma unroll
  for (int o = 1; o < 64; o <<= 1) {
    unsigned vv = __shfl_up(s, o);
    if ((t & 63) >= o) s += vv;
  }
  if ((t & 63) == 63) wsum[t >> 6] = s;
  __syncthreads();
  if (t == 0) {
    unsigned a = 0;
#pragma unroll
    for (int i = 0; i < 16; ++i) { unsigned vv = wsum[i]; wsum[i] = a; a += vv; }
  }
  __syncthreads();
  unsigned texcl = wsum[t >> 6] + (s - ts2);
  __syncthreads();
  arr[2 * t] = texcl;
  arr[2 * t + 1] = texcl + c0;
  __syncthreads();
}

// ---------------- wise3: one block per (half, dim) ----------------
// LDS (64KB exactly): zs[8192] | zoff[2048] | eoff[2048] | esidx[4096]
// (wsum aliases esidx[0:16] — esidx written only after both scans).
// Queries processed in bucket-sorted order for wave coherence; per-query
// best over this z-half stored to wbest[(h*DIM+d)*M_E + orig].
__global__ __launch_bounds__(1024, 4) void wise3_kernel(
    const float* __restrict__ zT, const float* __restrict__ eT,
    float* __restrict__ wbest) {
  extern __shared__ __align__(16) char smem[];
  float* zs = (float*)smem;                          // 8192
  unsigned* zoff = (unsigned*)(smem + 32768);        // 2048
  unsigned* eoff = zoff + NB;                        // 2048
  unsigned* esidx = eoff + NB;                       // 4096
  unsigned* wsum = esidx;                            // alias (16)

  const int h = blockIdx.x, d = blockIdx.y, t = threadIdx.x;

  for (int i = t; i < 2 * NB; i += 1024) zoff[i] = 0u;  // zoff+eoff contiguous
  __syncthreads();

  // load z half-column (8/thread, coalesced), histogram
  float zv[8];
  int zbk[8];
  const float4* p = (const float4*)(zT + (size_t)d * N_Z + (size_t)h * NZH);
#pragma unroll
  for (int i = 0; i < 2; ++i) {
    float4 v = p[i * 1024 + t];
    zv[4 * i + 0] = v.x; zv[4 * i + 1] = v.y; zv[4 * i + 2] = v.z; zv[4 * i + 3] = v.w;
  }
#pragma unroll
  for (int i = 0; i < 8; ++i) {
    zbk[i] = bucketFix(zv[i]);
    atomicAdd(&zoff[zbk[i]], 1u);
  }

  // load e column (4/thread, coalesced), histogram
  const float* ec = eT + (size_t)d * M_E;
  float ev4[4];
  int ebk[4];
#pragma unroll
  for (int i = 0; i < 4; ++i) {
    ev4[i] = ec[i * 1024 + t];
    ebk[i] = bucketFix(ev4[i]);
    atomicAdd(&eoff[ebk[i]], 1u);
  }
  __syncthreads();

  excl_scan_nb(zoff, wsum, t);
  excl_scan_nb(eoff, wsum, t);

  // scatter z values; scatter e ORIGINAL INDICES (stable id across halves)
#pragma unroll
  for (int i = 0; i < 8; ++i) {
    unsigned pos = atomicAdd(&zoff[zbk[i]], 1u);
    zs[pos] = zv[i];
  }
#pragma unroll
  for (int i = 0; i < 4; ++i) {
    unsigned pos = atomicAdd(&eoff[ebk[i]], 1u);
    esidx[pos] = (unsigned)(i * 1024 + t);
  }
  __syncthreads();
  // after scatter: zoff[b] = end(b); start(b) = b ? zoff[b-1] : 0

  float* wb = wbest + (size_t)(h * DIM + d) * M_E;
#pragma unroll 1
  for (int q = 0; q < 4; ++q) {
    int slot = q * 1024 + t;               // sorted order -> coherent lanes
    unsigned orig = esidx[slot];
    float ev = ec[orig];                   // L1/L2-hot gather (16KB column)
    int b0 = bucketFix(ev);
    unsigned s0 = b0 ? zoff[b0 - 1] : 0u;
    unsigned s1 = zoff[b0];
    float best2;
    {  // seeds: genuine z members adjacent in bucket order
      unsigned js = min(s0, (unsigned)(NZH - 1));
      float dd = zs[js] - ev;
      best2 = dd * dd;
      if (s0 > 0) { dd = zs[s0 - 1] - ev; best2 = fminf(best2, dd * dd); }
    }
    for (unsigned j = s0; j < s1; ++j) {
      float dd = zs[j] - ev;
      best2 = fminf(best2, dd * dd);
    }
    for (int r = 1; r < NB; ++r) {
      int bl = b0 - r, br = b0 + r;
      float edgeL = BMIN + (float)(bl + 1) * BW;  // all z in bl <= edgeL <= ev
      float edgeR = BMIN + (float)br * BW;        // all z in br >= edgeR >= ev
      float dL = ev - edgeL, dR = edgeR - ev;
      bool doL = (bl >= 0) && (dL * dL < best2);
      bool doR = (br < NB) && (dR * dR < best2);
      if (!doL && !doR) break;
      if (doL) {
        unsigned a0 = bl ? zoff[bl - 1] : 0u, a1 = zoff[bl];
        for (unsigned j = a0; j < a1; ++j) {
          float dd = zs[j] - ev;
          best2 = fminf(best2, dd * dd);
        }
      }
      if (doR) {
        unsigned a0 = zoff[br - 1], a1 = zoff[br];
        for (unsigned j = a0; j < a1; ++j) {
          float dd = zs[j] - ev;
          best2 = fminf(best2, dd * dd);
        }
      }
    }
    wb[orig] = best2;
  }
}

// ---------------- wreduce: min across halves, sum per dim ----------------
__global__ void wreduce_kernel(const float* __restrict__ wbest, float* __restrict__ wise_part) {
  __shared__ float red[4];
  const int d = blockIdx.x, t = threadIdx.x;
  const float4* a = (const float4*)(wbest + (size_t)d * M_E);
  const float4* b = (const float4*)(wbest + (size_t)(DIM + d) * M_E);
  float s = 0.0f;
#pragma unroll
  for (int j = 0; j < 4; ++j) {
    int i = j * 256 + t;
    float4 x = a[i], y = b[i];
    s += fminf(x.x, y.x) + fminf(x.y, y.y) + fminf(x.z, y.z) + fminf(x.w, y.w);
  }
#pragma unroll
  for (int o = 32; o; o >>= 1) s += __shfl_down(s, o);
  if ((t & 63) == 0) red[t >> 6] = s;
  __syncthreads();
  if (t == 0) atomicAdd(&wise_part[d & 63], red[0] + red[1] + red[2] + red[3]);
}

// ---------------- final reduce ----------------
__global__ void final_kernel(const unsigned* __restrict__ d2min,
                             const float* __restrict__ wise_part, float* __restrict__ out) {
  __shared__ float red[4];
  int t = threadIdx.x;
  float s = 0.0f;
  for (int m = t; m < M_E; m += 256) s += __uint_as_float(d2min[m]);
#pragma unroll
  for (int off = 32; off; off >>= 1) s += __shfl_down(s, off);
  if ((t & 63) == 0) red[t >> 6] = s;
  __syncthreads();
  if (t == 0) {
    float tot = red[0] + red[1] + red[2] + red[3];
    out[0] = tot / (float)M_E;
    float w = 0.0f;
    for (int i = 0; i < 64; ++i) w += wise_part[i];
    out[1] = w / ((float)M_E * (float)DIM);
  }
}

extern "C" void kernel_launch(void* const* d_in, const int* in_sizes, int n_in,
                              void* d_out, int out_size, void* d_ws, size_t ws_size,
                              hipStream_t stream) {
  const float* z = (const float*)d_in[0];
  const float* e = (const float*)d_in[1];
  float* out = (float*)d_out;

  char* ws = (char*)d_ws;
  unsigned short* zb = (unsigned short*)ws;                 // 8 MiB
  unsigned short* eb = (unsigned short*)(ws + 8388608);     // 2 MiB
  float* z2 = (float*)(ws + 10485760);                      // 64 KiB
  float* e2 = (float*)(ws + 10551296);                      // 16 KiB
  unsigned* d2min = (unsigned*)(ws + 10567680);             // 16 KiB
  float* wise_part = (float*)(ws + 10584064);               // 256 B
  float* zT = (float*)(ws + 11534336);                      // 16 MiB
  float* eT = (float*)(ws + 28311552);                      // 4 MiB -> 32505856
  float* wbest = (float*)(ws + 33554432);                   // 8 MiB -> 41943040

  const size_t LDS_WISE = 65536;
  static int attr_done = 0;
  if (!attr_done) {
    (void)hipFuncSetAttribute((const void*)wise3_kernel,
                              hipFuncAttributeMaxDynamicSharedMemorySize, (int)LDS_WISE);
    attr_done = 1;
  }

  init_kernel<<<64, 256, 0, stream>>>(d2min, wise_part, z2, e2);
  prep_kernel<<<dim3(N_Z / 32, DIM / 32), dim3(32, 8), 0, stream>>>(z, zT, zb, z2, N_Z);
  prep_kernel<<<dim3(M_E / 32, DIM / 32), dim3(32, 8), 0, stream>>>(e, eT, eb, e2, M_E);
  gemm_min_kernel<<<dim3(32, 128), 256, 0, stream>>>(zb, eb, z2, e2, d2min);
  wise3_kernel<<<dim3(2, DIM), 1024, LDS_WISE, stream>>>(zT, eT, wbest);
  wreduce_kernel<<<DIM, 256, 0, stream>>>(wbest, wise_part);
  final_kernel<<<1, 256, 0, stream>>>(d2min, wise_part, out);
}